// Round 9
// baseline (2143.778 us; speedup 1.0000x reference)
//
#include <hip/hip_runtime.h>
#include <hip/hip_bf16.h>
#include <math.h>

// Shapes
#define B_  16
#define S_  64
#define R_  6
#define L_  24
#define D_  128
#define H_  256
#define BS_   1024    // B*S
#define BSR_  6144    // B*S*R

typedef __attribute__((ext_vector_type(8))) short short8;
typedef __attribute__((ext_vector_type(4))) float f32x4;

__device__ __forceinline__ float sigmoidf_(float x) { return 1.f / (1.f + __expf(-x)); }
// fast tanh via __expf (no ocml libcall)
__device__ __forceinline__ float tanhf_(float x) {
    float e = __expf(2.f * x);
    return 1.f - 2.f / (e + 1.f);
}

// RNE float->bf16 helpers
__device__ __forceinline__ unsigned short f2bf(float f) {
    unsigned int u = __float_as_uint(f);
    u = (u + 0x7fff + ((u >> 16) & 1)) >> 16;
    return (unsigned short)u;
}
__device__ __forceinline__ unsigned int pack2(float a, float b) {
    unsigned int ua = __float_as_uint(a), ub = __float_as_uint(b);
    ua = (ua + 0x7fff + ((ua >> 16) & 1)) >> 16;
    ub = (ub + 0x7fff + ((ub >> 16) & 1)) & 0xffff0000u;
    return (ua & 0xffffu) | ub;
}

// ---------------------------------------------------------------------------
// fp32 tiled GEMM (small projections): C[m,n] = bias[n] + sum_k A(m,k)*B[n*ldb+k]
// A(m,k) = (k < K1) ? A1[m*lda1+k] : A2[m*lda2+(k-K1)]
// ---------------------------------------------------------------------------
#define BM 64
#define BN 64
#define BK 16

__global__ __launch_bounds__(256) void gemm_k(
    const float* __restrict__ A1, int lda1, int K1,
    const float* __restrict__ A2, int lda2,
    const float* __restrict__ Bm, int ldb,
    const float* __restrict__ bias,
    float* __restrict__ C, int ldc,
    int M, int N, int K)
{
    __shared__ float As[BK][BM + 4];
    __shared__ float Bs[BK][BN + 4];
    const int tid = threadIdx.x;
    const int m0 = blockIdx.x * BM;
    const int n0 = blockIdx.y * BN;
    const int tx = tid & 15, ty = tid >> 4;
    const int lr  = tid >> 2;
    const int lk0 = (tid & 3) << 2;
    float acc[4][4] = {};

    for (int k0 = 0; k0 < K; k0 += BK) {
        #pragma unroll
        for (int i = 0; i < 4; ++i) {
            int k = k0 + lk0 + i;
            int m = m0 + lr;
            float va = 0.f;
            if (m < M && k < K)
                va = (k < K1) ? A1[(size_t)m * lda1 + k]
                              : A2[(size_t)m * lda2 + (k - K1)];
            As[lk0 + i][lr] = va;
            int nn = n0 + lr;
            float vb = 0.f;
            if (nn < N && k < K) vb = Bm[(size_t)nn * ldb + k];
            Bs[lk0 + i][lr] = vb;
        }
        __syncthreads();
        #pragma unroll
        for (int kk = 0; kk < BK; ++kk) {
            const float4 a4 = *(const float4*)&As[kk][ty << 2];
            const float4 b4 = *(const float4*)&Bs[kk][tx << 2];
            const float a[4] = {a4.x, a4.y, a4.z, a4.w};
            const float b[4] = {b4.x, b4.y, b4.z, b4.w};
            #pragma unroll
            for (int i = 0; i < 4; ++i)
                #pragma unroll
                for (int j = 0; j < 4; ++j)
                    acc[i][j] = fmaf(a[i], b[j], acc[i][j]);
        }
        __syncthreads();
    }
    #pragma unroll
    for (int i = 0; i < 4; ++i) {
        int m = m0 + (ty << 2) + i;
        if (m >= M) continue;
        #pragma unroll
        for (int j = 0; j < 4; ++j) {
            int nn = n0 + (tx << 2) + j;
            if (nn < N) C[(size_t)m * ldc + nn] = acc[i][j] + bias[nn];
        }
    }
}

// ---------------------------------------------------------------------------
// Wbig bf16 (1024 x 384) + biasb fp32 (1024), interleaved gate quadruples
// ---------------------------------------------------------------------------
__global__ void prep_wbig(const float* __restrict__ w_ih, const float* __restrict__ w_hh,
                          const float* __restrict__ b_ih, const float* __restrict__ b_hh,
                          unsigned short* __restrict__ Wbg, float* __restrict__ biasb)
{
    int idx = blockIdx.x * 256 + threadIdx.x;
    if (idx >= 1024 * 384) return;
    int row = idx / 384, k = idx % 384;
    int j = row >> 2, c = row & 3;
    float v = 0.f;
    if (c == 0)      v = (k < 128) ? w_ih[j * 128 + k]          : w_hh[j * 256 + (k - 128)];
    else if (c == 1) v = (k < 128) ? w_ih[(256 + j) * 128 + k]  : w_hh[(256 + j) * 256 + (k - 128)];
    else if (c == 2) v = (k < 128) ? w_ih[(512 + j) * 128 + k]  : 0.f;
    else             v = (k < 128) ? 0.f                         : w_hh[(512 + j) * 256 + (k - 128)];
    Wbg[idx] = f2bf(v);
    if (k == 0) {
        float bb;
        if (c == 0)      bb = b_ih[j] + b_hh[j];
        else if (c == 1) bb = b_ih[256 + j] + b_hh[256 + j];
        else if (c == 2) bb = b_ih[512 + j];
        else             bb = b_hh[512 + j];
        biasb[row] = bb;
    }
}

// w_hh -> bf16, natural row order (768 x 256)
__global__ void prep_whh(const float* __restrict__ w, unsigned short* __restrict__ wb)
{
    int idx = blockIdx.x * 256 + threadIdx.x;
    if (idx < 768 * 256) wb[idx] = f2bf(w[idx]);
}

// ---------------------------------------------------------------------------
// Inter-GRU step (bench-verified):
// C(6144x1024) = [x_t | h_t](bf16) @ Wbig^T + fused gate epilogue.
// MFMA 16x16x32; tile 64x128, 4 waves (1x4), BK=32, dbuf LDS, 80B rows.
// ---------------------------------------------------------------------------
__global__ __launch_bounds__(256) void gru_step(
    const float* __restrict__ his,            // (6144,24,128) fp32
    const unsigned short* __restrict__ Wbg,   // (1024,384) bf16
    const float* __restrict__ biasb,          // (1024)
    const unsigned short* __restrict__ hcur,  // (6144,256) bf16
    unsigned short* __restrict__ hnxt,        // (6144,256) bf16
    float* __restrict__ hfp,                  // (6144,256) fp32, in-place state
    float* __restrict__ his_last,             // (6144,256) fp32
    const int* __restrict__ len, int t)
{
    __shared__ __align__(16) char lds[30720];
    const int tid = threadIdx.x;
    const int lane = tid & 63, wn = tid >> 6;
    const int l15 = lane & 15, l4 = lane >> 4;
    const int m0 = blockIdx.x * 64, n0 = blockIdx.y * 128;

    const int r_ = tid >> 2, c_ = tid & 3;

    const int A0 = 0, A1 = 5120, W0 = 10240, W1 = 20480;

    f32x4 acc[4][2] = {};

    auto loadA = [&](int ks, int row, int kc) -> uint4 {
        if (ks < 4) {
            const float* p = his + ((size_t)(m0 + row) * 24 + t) * 128 + ks * 32 + kc * 8;
            float4 f0 = *(const float4*)p;
            float4 f1 = *(const float4*)(p + 4);
            uint4 r;
            r.x = pack2(f0.x, f0.y); r.y = pack2(f0.z, f0.w);
            r.z = pack2(f1.x, f1.y); r.w = pack2(f1.z, f1.w);
            return r;
        }
        return *(const uint4*)(hcur + (size_t)(m0 + row) * 256 + (ks - 4) * 32 + kc * 8);
    };
    auto loadW = [&](int ks, int row, int kc) -> uint4 {
        return *(const uint4*)(Wbg + (size_t)(n0 + row) * 384 + ks * 32 + kc * 8);
    };
    auto stq = [&](int base, int row, int kc, uint4 v) {
        *(uint4*)(lds + base + row * 80 + kc * 16) = v;
    };

    {
        uint4 a1 = loadA(0, r_, c_);
        uint4 w1 = loadW(0, r_, c_), w2 = loadW(0, r_ + 64, c_);
        stq(A0, r_, c_, a1); stq(W0, r_, c_, w1); stq(W0, r_ + 64, c_, w2);
    }
    __syncthreads();

    for (int ks = 0; ks < 12; ++ks) {
        const int cb = ks & 1;
        uint4 a1, w1, w2;
        if (ks < 11) {
            a1 = loadA(ks + 1, r_, c_);
            w1 = loadW(ks + 1, r_, c_); w2 = loadW(ks + 1, r_ + 64, c_);
        }
        const int ab = cb ? A1 : A0;
        const int wb = cb ? W1 : W0;
        short8 af[4], bfr[2];
        #pragma unroll
        for (int i = 0; i < 4; ++i)
            af[i]  = *(const short8*)(lds + ab + (i * 16 + l15) * 80 + l4 * 16);
        #pragma unroll
        for (int j = 0; j < 2; ++j)
            bfr[j] = *(const short8*)(lds + wb + (wn * 32 + j * 16 + l15) * 80 + l4 * 16);
        #pragma unroll
        for (int i = 0; i < 4; ++i)
            #pragma unroll
            for (int j = 0; j < 2; ++j)
                acc[i][j] = __builtin_amdgcn_mfma_f32_16x16x32_bf16(af[i], bfr[j], acc[i][j], 0, 0, 0);
        if (ks < 11) {
            const int nab = cb ? A0 : A1;
            const int nwb = cb ? W0 : W1;
            stq(nab, r_, c_, a1); stq(nwb, r_, c_, w1); stq(nwb, r_ + 64, c_, w2);
        }
        __syncthreads();
    }

    #pragma unroll
    for (int mi = 0; mi < 4; ++mi) {
        const int mb = m0 + mi * 16 + l4 * 4;
        #pragma unroll
        for (int ni = 0; ni < 2; ++ni) {
            const int colg = n0 + wn * 32 + ni * 16 + l15;
            const float bs = biasb[colg];
            #pragma unroll
            for (int j = 0; j < 4; ++j) {
                float s  = acc[mi][ni][j] + bs;
                float s1 = __shfl_xor(s, 1);
                float s2 = __shfl_xor(s, 2);
                float s3 = __shfl_xor(s, 3);
                if ((lane & 3) == 0) {
                    const int m = mb + j;
                    const int u = colg >> 2;
                    float r  = sigmoidf_(s);
                    float z  = sigmoidf_(s1);
                    float ng = tanhf_(s2 + r * s3);
                    float hp = hfp[(size_t)m * 256 + u];
                    float hn = (1.f - z) * ng + z * hp;
                    hfp[(size_t)m * 256 + u] = hn;
                    hnxt[(size_t)m * 256 + u] = f2bf(hn);
                    if (t == len[m] - 1) his_last[(size_t)m * 256 + u] = hn;
                }
            }
        }
    }
}

// ---------------------------------------------------------------------------
// Intra GRU v2: persistent single-block MFMA kernel, xw software-pipelined
// one step ahead (named A/B register sets), G padded to stride 770 (2-way max).
// ---------------------------------------------------------------------------
#define GS 770

#define LOADXW(T, XR, XZ, XN) { \
    _Pragma("unroll") \
    for (int p = 0; p < 8; ++p) { \
        const float* xp = xw + ((size_t)((q + 2 * p) << 6) + (T)) * 768 + u; \
        XR[p] = xp[0]; XZ[p] = xp[256]; XN[p] = xp[512]; \
    } }

#define MFMA_PHASE() { \
    f32x4 acc[6] = {}; \
    _Pragma("unroll") \
    for (int kk = 0; kk < 8; ++kk) { \
        short8 a = *(const short8*)&hs_bf[l15 * 264 + kk * 32 + l4 * 8]; \
        _Pragma("unroll") \
        for (int ni = 0; ni < 6; ++ni) \
            acc[ni] = __builtin_amdgcn_mfma_f32_16x16x32_bf16(a, wfr[ni][kk], acc[ni], 0, 0, 0); \
    } \
    _Pragma("unroll") \
    for (int ni = 0; ni < 6; ++ni) \
        _Pragma("unroll") \
        for (int j = 0; j < 4; ++j) \
            G[(l4 * 4 + j) * GS + cw + ni * 16 + l15] = acc[ni][j]; \
    }

#define GATE_PHASE(T, XR, XZ, XN) { \
    _Pragma("unroll") \
    for (int p = 0; p < 8; ++p) { \
        const int m = q + 2 * p; \
        float r = sigmoidf_(XR[p] + G[m * GS + u] + br); \
        float z = sigmoidf_(XZ[p] + G[m * GS + 256 + u] + bz); \
        float n = tanhf_(XN[p] + r * (G[m * GS + 512 + u] + bn)); \
        float hold = hf[m * 256 + u]; \
        float hnew = (1.f - z) * n + z * hold; \
        hf[m * 256 + u] = hnew; \
        hs_bf[m * 264 + u] = f2bf(hnew); \
        ih[(size_t)((m << 6) + (T)) * 256 + u] = hnew; \
    } }

__global__ __launch_bounds__(512, 2) void intra_gru_mfma(
    const unsigned short* __restrict__ whhb,  // (768,256) bf16, rows [r|z|n]
    const float* __restrict__ b_hh,           // (768)
    const float* __restrict__ xw,             // (1024,768) fp32 [xr|xz|xn]
    float* __restrict__ ih)                   // (1024,256) fp32
{
    __shared__ __align__(16) unsigned short hs_bf[16 * 264];
    __shared__ float hf[16 * 256];
    __shared__ float G[16 * GS];
    const int tid = threadIdx.x;
    const int lane = tid & 63, wv = tid >> 6;
    const int l15 = lane & 15, l4 = lane >> 4;
    const int cw = wv * 96;

    short8 wfr[6][8];
    #pragma unroll
    for (int ni = 0; ni < 6; ++ni)
        #pragma unroll
        for (int kk = 0; kk < 8; ++kk)
            wfr[ni][kk] = *(const short8*)(whhb + (size_t)(cw + ni * 16 + l15) * 256 + kk * 32 + l4 * 8);

    const int u = tid & 255, q = tid >> 8;
    const float br = b_hh[u], bz = b_hh[256 + u], bn = b_hh[512 + u];

    #pragma unroll
    for (int p = 0; p < 8; ++p) hf[tid + p * 512] = 0.f;
    #pragma unroll
    for (int p = 0; p < 9; ++p) { int i = tid + p * 512; if (i < 16 * 264) hs_bf[i] = 0; }
    __syncthreads();

    float xrA[8], xzA[8], xnA[8], xrB[8], xzB[8], xnB[8];
    LOADXW(0, xrA, xzA, xnA);

    for (int t = 0; t < S_; t += 2) {
        // step t: uses A set; prefetch t+1 into B (covered by full step)
        LOADXW(t + 1, xrB, xzB, xnB);
        MFMA_PHASE();
        __syncthreads();
        GATE_PHASE(t, xrA, xzA, xnA);
        __syncthreads();
        // step t+1: uses B set; prefetch t+2 into A
        if (t + 2 < S_) LOADXW(t + 2, xrA, xzA, xnA);
        MFMA_PHASE();
        __syncthreads();
        GATE_PHASE(t + 1, xrB, xzB, xnB);
        __syncthreads();
    }
}

// ---------------------------------------------------------------------------
// Concat / pack kernels (fp32, R7 known-good)
// ---------------------------------------------------------------------------
__global__ void concat_mrv(const float* __restrict__ hl, const float* __restrict__ ir,
                           float* __restrict__ Mrv)
{
    int idx = blockIdx.x * 256 + threadIdx.x;          // BSR_*384
    if (idx >= BSR_ * 384) return;
    int c = idx % 384, pr = idx / 384;
    Mrv[idx] = (c < 256) ? hl[(size_t)pr * 256 + c] : ir[(size_t)pr * 128 + (c - 256)];
}

__global__ void concat_mpv(const float* __restrict__ ihf, const float* __restrict__ x,
                           float* __restrict__ mpv)
{
    int idx = blockIdx.x * 256 + threadIdx.x;          // BS_*384
    if (idx >= BS_ * 384) return;
    int c = idx % 384, p = idx / 384;
    float v = 0.f;
    if (c < 256)      v = ihf[(size_t)p * 256 + c];
    else if (c < 383) v = x[(size_t)p * 128 + (c - 256)];
    mpv[idx] = v;
}

__global__ void concat_ihp(const float* __restrict__ ihf, const float* __restrict__ x,
                           float* __restrict__ ihp)
{
    int idx = blockIdx.x * 256 + threadIdx.x;          // BS_*260
    if (idx >= BS_ * 260) return;
    int c = idx % 260, p = idx / 260;
    float v = 0.f;
    if (c < 256)       v = ihf[(size_t)p * 256 + c];
    else if (c == 256) v = x[(size_t)p * 128 + 127];
    ihp[idx] = v;
}

__global__ void combine_feat(const float* __restrict__ vv, const float* __restrict__ vh,
                             const float* __restrict__ ihf, const float* __restrict__ x,
                             const float* __restrict__ wr, float* __restrict__ feat)
{
    int idx = blockIdx.x * 256 + threadIdx.x;          // BS_*640
    if (idx >= BS_ * 640) return;
    int c = idx % 640, p = idx / 640;
    float e0 = __expf(wr[0]), e1 = __expf(wr[1]);
    float w0 = e0 / (e0 + e1), w1 = e1 / (e0 + e1);
    float v = 0.f;
    if (c < 256)      v = w0 * vv[(size_t)p * 256 + c] + w1 * vh[(size_t)p * 256 + c];
    else if (c < 512) v = ihf[(size_t)p * 256 + (c - 256)];
    else if (c < 639) v = x[(size_t)p * 128 + (c - 512)];
    feat[idx] = v;
}

// ---------------------------------------------------------------------------
// v_v attention: R=6 keys, 1 query per (p, head). One wave per (p, head).
// ---------------------------------------------------------------------------
__global__ __launch_bounds__(256) void attn_vv(
    const float* __restrict__ q, const float* __restrict__ k,
    const float* __restrict__ v, float* __restrict__ o)
{
    int wid = (blockIdx.x * 256 + threadIdx.x) >> 6;
    int lane = threadIdx.x & 63;
    int p = wid >> 1, head = wid & 1;
    int d0 = head * 128 + lane * 2;
    const float* qp = q + (size_t)p * 256 + d0;
    float q0 = qp[0], q1 = qp[1];
    float sc[R_];
    #pragma unroll
    for (int r = 0; r < R_; ++r) {
        const float* kp = k + (size_t)(p * R_ + r) * 256 + d0;
        float s = q0 * kp[0] + q1 * kp[1];
        #pragma unroll
        for (int off = 32; off; off >>= 1) s += __shfl_xor(s, off, 64);
        sc[r] = s * 0.08838834764831845f;
    }
    float mx = sc[0];
    #pragma unroll
    for (int r = 1; r < R_; ++r) mx = fmaxf(mx, sc[r]);
    float sum = 0.f;
    #pragma unroll
    for (int r = 0; r < R_; ++r) { sc[r] = __expf(sc[r] - mx); sum += sc[r]; }
    float inv = 1.f / sum;
    float o0 = 0.f, o1 = 0.f;
    #pragma unroll
    for (int r = 0; r < R_; ++r) {
        const float* vp = v + (size_t)(p * R_ + r) * 256 + d0;
        o0 += sc[r] * vp[0];
        o1 += sc[r] * vp[1];
    }
    o[(size_t)p * 256 + d0]     = o0 * inv;
    o[(size_t)p * 256 + d0 + 1] = o1 * inv;
}

// ---------------------------------------------------------------------------
// v_h attention: causal 64x64 per (b, head). One wave per (b, head, q-row).
// ---------------------------------------------------------------------------
__global__ __launch_bounds__(256) void attn_vh(
    const float* __restrict__ q, const float* __restrict__ k,
    const float* __restrict__ v, float* __restrict__ o)
{
    __shared__ float ps[4][64];
    int widb = threadIdx.x >> 6;
    int wid = blockIdx.x * 4 + widb;
    int lane = threadIdx.x & 63;
    int b = wid >> 7;
    int rem = wid & 127;
    int head = rem >> 6;
    int qi = rem & 63;
    const float* qrow = q + ((size_t)b * 64 + qi) * 256 + head * 128;
    const float* krow = k + ((size_t)b * 64 + lane) * 256 + head * 128;
    float sA = 0.f, sB = 0.f;
    for (int d = 0; d < 128; d += 2) {
        sA = fmaf(qrow[d],     krow[d],     sA);
        sB = fmaf(qrow[d + 1], krow[d + 1], sB);
    }
    float s = (sA + sB) * 0.08838834764831845f;
    bool valid = (lane <= qi);
    float smax = valid ? s : -1e30f;
    #pragma unroll
    for (int off = 32; off; off >>= 1) smax = fmaxf(smax, __shfl_xor(smax, off, 64));
    float e = valid ? __expf(s - smax) : 0.f;
    float ssum = e;
    #pragma unroll
    for (int off = 32; off; off >>= 1) ssum += __shfl_xor(ssum, off, 64);
    float pv = e / ssum;
    ps[widb][lane] = pv;
    __syncthreads();
    float o0 = 0.f, o1 = 0.f;
    for (int j = 0; j <= qi; ++j) {
        float pj = ps[widb][j];
        const float* vrow = v + ((size_t)b * 64 + j) * 256 + head * 128;
        o0 = fmaf(pj, vrow[lane],      o0);
        o1 = fmaf(pj, vrow[lane + 64], o1);
    }
    o[((size_t)b * 64 + qi) * 256 + head * 128 + lane]      = o0;
    o[((size_t)b * 64 + qi) * 256 + head * 128 + lane + 64] = o1;
}

// ---------------------------------------------------------------------------
extern "C" void kernel_launch(void* const* d_in, const int* in_sizes, int n_in,
                              void* d_out, int out_size, void* d_ws, size_t ws_size,
                              hipStream_t stream)
{
    const float* intra_x   = (const float*)d_in[0];
    const float* inter_his = (const float*)d_in[1];
    const float* inter_r   = (const float*)d_in[2];
    const int*   inter_len = (const int*)  d_in[4];
    const float* w_ih = (const float*)d_in[5];
    const float* w_hh = (const float*)d_in[6];
    const float* b_ih = (const float*)d_in[7];
    const float* b_hh = (const float*)d_in[8];
    const float* iq_w = (const float*)d_in[9];
    const float* iq_b = (const float*)d_in[10];
    const float* ik_w = (const float*)d_in[11];
    const float* ik_b = (const float*)d_in[12];
    const float* iv_w = (const float*)d_in[13];
    const float* iv_b = (const float*)d_in[14];
    const float* io_w = (const float*)d_in[15];
    const float* io_b = (const float*)d_in[16];
    const float* aq_w = (const float*)d_in[17];
    const float* aq_b = (const float*)d_in[18];
    const float* ak_w = (const float*)d_in[19];
    const float* ak_b = (const float*)d_in[20];
    const float* av_w = (const float*)d_in[21];
    const float* av_b = (const float*)d_in[22];
    const float* ao_w = (const float*)d_in[23];
    const float* ao_b = (const float*)d_in[24];
    const float* wr   = (const float*)d_in[25];
    const float* ln_w = (const float*)d_in[26];
    const float* ln_b = (const float*)d_in[27];
    float* out = (float*)d_out;

    char* ws = (char*)d_ws;
    size_t off = 0;
    auto alloc = [&](size_t bytes) -> void* {
        char* p = ws + off;
        off += (bytes + 255) & ~(size_t)255;
        return (void*)p;
    };
    unsigned short* Wbg  = (unsigned short*)alloc((size_t)1024 * 384 * 2);
    unsigned short* whhb = (unsigned short*)alloc((size_t)768 * 256 * 2);
    float* biasb   = (float*)alloc(1024 * 4);
    unsigned short* hbf0 = (unsigned short*)alloc((size_t)BSR_ * H_ * 2);
    unsigned short* hbf1 = (unsigned short*)alloc((size_t)BSR_ * H_ * 2);
    float* hfp     = (float*)alloc((size_t)BSR_ * H_ * 4);
    float* hislast = (float*)alloc((size_t)BSR_ * H_ * 4);
    float* intraH  = (float*)alloc((size_t)BS_ * H_ * 4);
    float* xwI     = (float*)alloc((size_t)BS_ * 768 * 4);
    float* Mrv     = (float*)alloc((size_t)BSR_ * 384 * 4);
    float* mpv     = (float*)alloc((size_t)BS_ * 384 * 4);
    float* qbuf    = (float*)alloc((size_t)BS_ * 256 * 4);
    float* kbuf    = (float*)alloc((size_t)BSR_ * 256 * 4);
    float* vbuf    = (float*)alloc((size_t)BSR_ * 256 * 4);
    float* attno   = (float*)alloc((size_t)BS_ * 256 * 4);
    float* vv      = (float*)alloc((size_t)BS_ * 256 * 4);
    float* ihp     = (float*)alloc((size_t)BS_ * 260 * 4);
    float* qa      = (float*)alloc((size_t)BS_ * 256 * 4);
    float* ka      = (float*)alloc((size_t)BS_ * 256 * 4);
    float* va      = (float*)alloc((size_t)BS_ * 256 * 4);
    float* aho     = (float*)alloc((size_t)BS_ * 256 * 4);
    float* vhb     = (float*)alloc((size_t)BS_ * 256 * 4);
    float* feat    = (float*)alloc((size_t)BS_ * 640 * 4);
    (void)ws_size; (void)in_sizes; (void)n_in; (void)out_size;

    auto gemm = [&](const float* A, int lda, const float* Bw, int ldb,
                    const float* bias, float* C, int M, int N, int K) {
        gemm_k<<<dim3((M + BM - 1) / BM, (N + BN - 1) / BN), 256, 0, stream>>>(
            A, lda, K, A, 0, Bw, ldb, bias, C, N, M, N, K);
    };

    // weight prep + state init
    prep_wbig<<<1536, 256, 0, stream>>>(w_ih, w_hh, b_ih, b_hh, Wbg, biasb);
    prep_whh<<<768, 256, 0, stream>>>(w_hh, whhb);
    hipMemsetAsync(hbf0, 0, (size_t)BSR_ * H_ * 2, stream);
    hipMemsetAsync(hfp,  0, (size_t)BSR_ * H_ * 4, stream);

    // intra GRU: x-projection GEMM + persistent MFMA recurrence (pipelined)
    gemm(intra_x, 128, w_ih, 128, b_ih, xwI, BS_, 768, 128);
    intra_gru_mfma<<<1, 512, 0, stream>>>(whhb, b_hh, xwI, intraH);

    // inter GRU: 24 MFMA steps with fused gate epilogue
    for (int t = 0; t < L_; ++t) {
        const unsigned short* hc = (t & 1) ? hbf1 : hbf0;
        unsigned short* hx       = (t & 1) ? hbf0 : hbf1;
        gru_step<<<dim3(BSR_ / 64, 1024 / 128), 256, 0, stream>>>(
            inter_his, Wbg, biasb, hc, hx, hfp, hislast, inter_len, t);
    }

    // v_v branch (fp32 projections, R7 known-good path)
    concat_mrv<<<(BSR_ * 384 + 255) / 256, 256, 0, stream>>>(hislast, inter_r, Mrv);
    concat_mpv<<<(BS_ * 384 + 255) / 256, 256, 0, stream>>>(intraH, intra_x, mpv);
    gemm(mpv, 384, iq_w, 383, iq_b, qbuf, BS_, 256, 383);
    gemm(Mrv, 384, ik_w, 383, ik_b, kbuf, BSR_, 256, 383);
    gemm(Mrv, 384, iv_w, 384, iv_b, vbuf, BSR_, 256, 384);
    attn_vv<<<512, 256, 0, stream>>>(qbuf, kbuf, vbuf, attno);
    gemm(attno, 256, io_w, 256, io_b, vv, BS_, 256, 256);

    // v_h branch
    concat_ihp<<<(BS_ * 260 + 255) / 256, 256, 0, stream>>>(intraH, intra_x, ihp);
    gemm(intra_x, 128, aq_w, 127, aq_b, qa, BS_, 256, 127);
    gemm(intra_x, 128, ak_w, 127, ak_b, ka, BS_, 256, 127);
    gemm(ihp, 260, av_w, 257, av_b, va, BS_, 256, 257);
    attn_vh<<<512, 256, 0, stream>>>(qa, ka, va, aho);
    gemm(aho, 256, ao_w, 256, ao_b, vhb, BS_, 256, 256);

    // combine + final projection
    combine_feat<<<(BS_ * 640 + 255) / 256, 256, 0, stream>>>(vv, vhb, intraH, intra_x, wr, feat);
    gemm(feat, 640, ln_w, 639, ln_b, out, BS_, 256, 639);
}